// Round 12
// baseline (280.302 us; speedup 1.0000x reference)
//
#include <hip/hip_runtime.h>

typedef unsigned short ushort_t;
typedef __bf16 bf16_t;
typedef __attribute__((ext_vector_type(8))) bf16_t bf16x8;
typedef __attribute__((ext_vector_type(4))) float f32x4;

__device__ __forceinline__ ushort_t f2bf(float f) {
  unsigned int u = __builtin_bit_cast(unsigned int, f);
  u += 0x7FFFu + ((u >> 16) & 1u);
  return (ushort_t)(u >> 16);
}

__device__ __forceinline__ float bf2f(ushort_t s) {
  return __builtin_bit_cast(float, (unsigned int)s << 16);
}

__device__ __forceinline__ f32x4 mfma16(bf16x8 a, bf16x8 b, f32x4 c) {
  return __builtin_amdgcn_mfma_f32_16x16x32_bf16(a, b, c, 0, 0, 0);
}

__device__ __forceinline__ void async_copy16(const void* g, void* l) {
  __builtin_amdgcn_global_load_lds(
      (const __attribute__((address_space(1))) unsigned int*)g,
      (__attribute__((address_space(3))) unsigned int*)l,
      16, 0, 0);
}

#define BARRIER { __builtin_amdgcn_s_barrier(); asm volatile("" ::: "memory"); }
#define VMW3 asm volatile("s_waitcnt vmcnt(3)" ::: "memory")
#define VMW0 asm volatile("s_waitcnt vmcnt(0)" ::: "memory")

// device-scope grid barrier (all blocks co-resident by construction)
__device__ __forceinline__ void gsync(unsigned* cnt, unsigned want) {
  __syncthreads();
  if (threadIdx.x == 0) {
    __threadfence();                       // release: flush my phase's writes
    atomicAdd(cnt, 1u);
    while (atomicAdd(cnt, 0u) < want) __builtin_amdgcn_s_sleep(8);
  }
  __syncthreads();
  __threadfence();                         // acquire: invalidate for fresh reads
}

// ====== fused converts: x->bf16, w_qkv KV-cols -> wqt^T, Wq rows -> wqr ======
__global__ __launch_bounds__(256) void conv_all_k(const float* __restrict__ x,
                                                  const float* __restrict__ w,
                                                  ushort_t* __restrict__ xb,
                                                  ushort_t* __restrict__ wqt,
                                                  ushort_t* __restrict__ wqr) {
  __shared__ float lds[64][65];
  const int bid = blockIdx.x;
  const int tid = threadIdx.x;
  if (bid < 3072) {                      // x -> bf16
    int i = (bid * 256 + tid) * 8;
    float4 f0 = *(const float4*)(x + i);
    float4 f1 = *(const float4*)(x + i + 4);
    union { ushort_t s[8]; uint4 v; } u;
    u.s[0] = f2bf(f0.x); u.s[1] = f2bf(f0.y); u.s[2] = f2bf(f0.z); u.s[3] = f2bf(f0.w);
    u.s[4] = f2bf(f1.x); u.s[5] = f2bf(f1.y); u.s[6] = f2bf(f1.z); u.s[7] = f2bf(f1.w);
    *(uint4*)(xb + i) = u.v;
  } else if (bid < 3360) {               // K,V cols transpose: 24 x 12 tiles
    const int ii = bid - 3072;
    const int n0 = 768 + (ii % 24) * 64;
    const int k0 = (ii / 24) * 64;
#pragma unroll
    for (int q = 0; q < 16; ++q) {
      int lin = tid + q * 256;
      int i = lin >> 6, j = lin & 63;
      lds[i][j] = w[(size_t)(k0 + i) * 2304 + n0 + j];
    }
    __syncthreads();
#pragma unroll
    for (int q = 0; q < 16; ++q) {
      int lin = tid + q * 256;
      int jj = lin >> 6, kk = lin & 63;
      wqt[(size_t)(n0 + jj) * 768 + k0 + kk] = f2bf(lds[kk][jj]);
    }
  } else {                               // Wq rows (k-contig): 288 blocks
    int i = ((bid - 3360) * 256 + tid) * 8;
    int row = i / 768, col = i % 768;
    const float* src = w + (size_t)row * 2304 + col;
    float4 f0 = *(const float4*)src;
    float4 f1 = *(const float4*)(src + 4);
    union { ushort_t s[8]; uint4 v; } u;
    u.s[0] = f2bf(f0.x); u.s[1] = f2bf(f0.y); u.s[2] = f2bf(f0.z); u.s[3] = f2bf(f0.w);
    u.s[4] = f2bf(f1.x); u.s[5] = f2bf(f1.y); u.s[6] = f2bf(f1.z); u.s[7] = f2bf(f1.w);
    *(uint4*)(wqr + i) = u.v;
  }
}

// =============== 256x192 8-phase GEMM (BN=192, 112 KiB LDS) ===============
// C[z] = A[z] @ Bt[z]^T + bias[z]. K = 128*NIT, NIT >= 2. grid.x % 8 == 0.
template <bool OUT_BF16>
__global__ __launch_bounds__(512, 2) void g256x192_k(
    const ushort_t* __restrict__ A, int lda, long long sA,
    const ushort_t* __restrict__ Bt, int ldb, long long sB,
    const float* __restrict__ bias, long long sBias,
    void* __restrict__ Cp, int ldc, long long sC,
    int K, int ntiles) {
  __shared__ char smem[114688];  // 2 x (A 32K + B 24K)
  const int tid = threadIdx.x;
  const int lane = tid & 63;
  const int wid = tid >> 6;
  const int l15 = lane & 15, lhi = lane >> 4;
  const int wr = wid >> 2, wc = wid & 3;
  const int sx = l15 & 7;

  const int nwg = gridDim.x;
  const int q = nwg >> 3;
  const int swz = (blockIdx.x & 7) * q + (blockIdx.x >> 3);
  const int mt = swz / ntiles, nt = swz % ntiles;
  const int m0 = mt << 8, n0 = nt * 192;
  const long long z = blockIdx.y;

  const ushort_t* Ab = A + z * sA;
  const ushort_t* Bb = Bt + z * sB;

  const int r0 = tid >> 3;
  const int sg = tid & 7;
  const int soff = (sg ^ (r0 & 7)) << 4;

#define STAGE_A(BUF, H, K0)                                                      \
  { const char* g0 = (const char*)(Ab + (size_t)(m0 + (H)*128 + r0) * lda + (K0)) + soff;      \
    const char* g1 = (const char*)(Ab + (size_t)(m0 + (H)*128 + r0 + 64) * lda + (K0)) + soff; \
    char* lb = smem + (BUF)*57344 + (H)*16384;                                   \
    async_copy16(g0, lb + tid * 16);                                             \
    async_copy16(g1, lb + 8192 + tid * 16); }

#define STAGE_B3(BUF, J, K0)                                                     \
  { const char* g0 = (const char*)(Bb + (size_t)(n0 + (J)*64 + r0) * ldb + (K0)) + soff;       \
    async_copy16(g0, smem + (BUF)*57344 + 32768 + (J)*8192 + tid * 16); }

  const int aBase = wr * 16384 + l15 * 128;
  const int bBase = 32768 + (wc * 48 + l15) * 128;
  const int sk0 = ((lhi ^ sx) << 4);
  const int sk1 = (((4 + lhi) ^ sx) << 4);

  f32x4 acc[8][3] = {};
  bf16x8 bfr[3][2];

#define DS_A(BUF, MPAIR, AF)                                                     \
  _Pragma("unroll") for (int mm = 0; mm < 2; ++mm) {                             \
    AF[mm][0] = *(const bf16x8*)(smem + (BUF)*57344 + aBase + ((MPAIR)*2+mm)*2048 + sk0); \
    AF[mm][1] = *(const bf16x8*)(smem + (BUF)*57344 + aBase + ((MPAIR)*2+mm)*2048 + sk1); }

#define DS_B(BUF)                                                                \
  _Pragma("unroll") for (int n = 0; n < 3; ++n) {                                \
    bfr[n][0] = *(const bf16x8*)(smem + (BUF)*57344 + bBase + n*2048 + sk0);     \
    bfr[n][1] = *(const bf16x8*)(smem + (BUF)*57344 + bBase + n*2048 + sk1); }

#define MFMA_PH(MPAIR, AF)                                                       \
  __builtin_amdgcn_s_setprio(1);                                                 \
  _Pragma("unroll") for (int mm = 0; mm < 2; ++mm)                               \
    _Pragma("unroll") for (int n = 0; n < 3; ++n) {                              \
      acc[(MPAIR)*2+mm][n] = mfma16(AF[mm][0], bfr[n][0], acc[(MPAIR)*2+mm][n]); \
      acc[(MPAIR)*2+mm][n] = mfma16(AF[mm][1], bfr[n][1], acc[(MPAIR)*2+mm][n]); } \
  __builtin_amdgcn_s_setprio(0);

  STAGE_A(0, 0, 0) STAGE_A(0, 1, 0)
  STAGE_B3(0, 0, 0) STAGE_B3(0, 1, 0) STAGE_B3(0, 2, 0)
  STAGE_B3(1, 0, 64) STAGE_B3(1, 1, 64) STAGE_B3(1, 2, 64)
  VMW3;
  BARRIER

  const int NIT = K >> 7;
#pragma unroll 1
  for (int it = 0; it < NIT - 1; ++it) {
    const int kA = (it << 7) + 64;
    const int k2 = (it << 7) + 128;
    const int k3 = (it << 7) + 192;
    { bf16x8 af[2][2]; DS_B(0) DS_A(0, 0, af) STAGE_A(1, 0, kA)
      BARRIER MFMA_PH(0, af) BARRIER }
    { bf16x8 af[2][2]; DS_A(0, 1, af) STAGE_A(1, 1, kA)
      BARRIER MFMA_PH(1, af) BARRIER }
    { bf16x8 af[2][2]; DS_A(0, 2, af) STAGE_B3(0, 0, k2) STAGE_B3(0, 1, k2)
      BARRIER MFMA_PH(2, af) BARRIER }
    { bf16x8 af[2][2]; DS_A(0, 3, af) STAGE_B3(0, 2, k2) VMW3;
      BARRIER MFMA_PH(3, af) BARRIER }
    { bf16x8 af[2][2]; DS_B(1) DS_A(1, 0, af) STAGE_A(0, 0, k2)
      BARRIER MFMA_PH(0, af) BARRIER }
    { bf16x8 af[2][2]; DS_A(1, 1, af) STAGE_A(0, 1, k2)
      BARRIER MFMA_PH(1, af) BARRIER }
    { bf16x8 af[2][2]; DS_A(1, 2, af) STAGE_B3(1, 0, k3) STAGE_B3(1, 1, k3)
      BARRIER MFMA_PH(2, af) BARRIER }
    { bf16x8 af[2][2]; DS_A(1, 3, af) STAGE_B3(1, 2, k3) VMW3;
      BARRIER MFMA_PH(3, af) BARRIER }
  }
  {  // peeled epilogue: only A(buf1)@kA staged; VMW0 at ph4
    const int kA = ((NIT - 1) << 7) + 64;
    { bf16x8 af[2][2]; DS_B(0) DS_A(0, 0, af) STAGE_A(1, 0, kA)
      BARRIER MFMA_PH(0, af) BARRIER }
    { bf16x8 af[2][2]; DS_A(0, 1, af) STAGE_A(1, 1, kA)
      BARRIER MFMA_PH(1, af) BARRIER }
    { bf16x8 af[2][2]; DS_A(0, 2, af)
      BARRIER MFMA_PH(2, af) BARRIER }
    { bf16x8 af[2][2]; DS_A(0, 3, af) VMW0;
      BARRIER MFMA_PH(3, af) BARRIER }
    { bf16x8 af[2][2]; DS_B(1) DS_A(1, 0, af)
      BARRIER MFMA_PH(0, af) BARRIER }
    { bf16x8 af[2][2]; DS_A(1, 1, af)
      BARRIER MFMA_PH(1, af) BARRIER }
    { bf16x8 af[2][2]; DS_A(1, 2, af)
      BARRIER MFMA_PH(2, af) BARRIER }
    { bf16x8 af[2][2]; DS_A(1, 3, af)
      BARRIER MFMA_PH(3, af) BARRIER }
  }

  float bv[3];
#pragma unroll
  for (int n = 0; n < 3; ++n) bv[n] = bias[z * sBias + n0 + wc * 48 + n * 16 + l15];
#pragma unroll
  for (int m = 0; m < 8; ++m) {
#pragma unroll
    for (int n = 0; n < 3; ++n) {
#pragma unroll
      for (int ri = 0; ri < 4; ++ri) {
        int row = m0 + wr * 128 + m * 16 + lhi * 4 + ri;
        int col = n0 + wc * 48 + n * 16 + l15;
        float v = acc[m][n][ri] + bv[n];
        size_t ci = (size_t)z * sC + (size_t)row * ldc + col;
        if (OUT_BF16) ((ushort_t*)Cp)[ci] = f2bf(v);
        else          ((float*)Cp)[ci]    = v;
      }
    }
  }
#undef STAGE_A
#undef STAGE_B3
#undef DS_A
#undef DS_B
#undef MFMA_PH
}

// =============== 128x192 8-phase GEMM (BM=128, 80 KiB LDS) ===============
template <bool OUT_BF16>
__global__ __launch_bounds__(512, 2) void g128x192_k(
    const ushort_t* __restrict__ A, int lda, long long sA,
    const ushort_t* __restrict__ Bt, int ldb, long long sB,
    const float* __restrict__ bias, long long sBias,
    void* __restrict__ Cp, int ldc, long long sC,
    int K, int ntiles) {
  __shared__ char smem[81920];  // 2 x (A 16K + B 24K)
  const int tid = threadIdx.x;
  const int lane = tid & 63;
  const int wid = tid >> 6;
  const int l15 = lane & 15, lhi = lane >> 4;
  const int wr = wid >> 2, wc = wid & 3;
  const int sx = l15 & 7;

  const int nwg = gridDim.x;
  const int q = nwg >> 3;
  const int swz = (blockIdx.x & 7) * q + (blockIdx.x >> 3);
  const int mt = swz / ntiles, nt = swz % ntiles;
  const int m0 = mt << 7, n0 = nt * 192;
  const long long z = blockIdx.y;

  const ushort_t* Ab = A + z * sA;
  const ushort_t* Bb = Bt + z * sB;

  const int r0 = tid >> 3;
  const int sg = tid & 7;
  const int soff = (sg ^ (r0 & 7)) << 4;

#define STAGE_A1(BUF, K0)                                                        \
  { const char* g0 = (const char*)(Ab + (size_t)(m0 + r0) * lda + (K0)) + soff;               \
    const char* g1 = (const char*)(Ab + (size_t)(m0 + r0 + 64) * lda + (K0)) + soff;          \
    char* lb = smem + (BUF)*40960;                                               \
    async_copy16(g0, lb + tid * 16);                                             \
    async_copy16(g1, lb + 8192 + tid * 16); }

#define STAGE_B3(BUF, J, K0)                                                     \
  { const char* g0 = (const char*)(Bb + (size_t)(n0 + (J)*64 + r0) * ldb + (K0)) + soff;       \
    async_copy16(g0, smem + (BUF)*40960 + 16384 + (J)*8192 + tid * 16); }

  const int aBase = wr * 8192 + l15 * 128;
  const int bBase = 16384 + (wc * 48 + l15) * 128;
  const int sk0 = ((lhi ^ sx) << 4);
  const int sk1 = (((4 + lhi) ^ sx) << 4);

  f32x4 acc[4][3] = {};
  bf16x8 bfr[3][2];

#define DS_A1(BUF, M, AF)                                                        \
  { AF[0] = *(const bf16x8*)(smem + (BUF)*40960 + aBase + (M)*2048 + sk0);       \
    AF[1] = *(const bf16x8*)(smem + (BUF)*40960 + aBase + (M)*2048 + sk1); }

#define DS_B1(BUF)                                                               \
  _Pragma("unroll") for (int n = 0; n < 3; ++n) {                                \
    bfr[n][0] = *(const bf16x8*)(smem + (BUF)*40960 + bBase + n*2048 + sk0);     \
    bfr[n][1] = *(const bf16x8*)(smem + (BUF)*40960 + bBase + n*2048 + sk1); }

#define MFMA_PH1(M, AF)                                                          \
  __builtin_amdgcn_s_setprio(1);                                                 \
  _Pragma("unroll") for (int n = 0; n < 3; ++n) {                                \
    acc[M][n] = mfma16(AF[0], bfr[n][0], acc[M][n]);                             \
    acc[M][n] = mfma16(AF[1], bfr[n][1], acc[M][n]); }                           \
  __builtin_amdgcn_s_setprio(0);

  STAGE_A1(0, 0)
  STAGE_B3(0, 0, 0) STAGE_B3(0, 1, 0) STAGE_B3(0, 2, 0)
  STAGE_B3(1, 0, 64) STAGE_B3(1, 1, 64) STAGE_B3(1, 2, 64)
  VMW3;
  BARRIER

  const int NIT = K >> 7;
#pragma unroll 1
  for (int it = 0; it < NIT - 1; ++it) {
    const int kA = (it << 7) + 64;
    const int k2 = (it << 7) + 128;
    const int k3 = (it << 7) + 192;
    { bf16x8 af[2]; DS_B1(0) DS_A1(0, 0, af) STAGE_A1(1, kA)
      BARRIER MFMA_PH1(0, af) BARRIER }
    { bf16x8 af[2]; DS_A1(0, 1, af)
      BARRIER MFMA_PH1(1, af) BARRIER }
    { bf16x8 af[2]; DS_A1(0, 2, af) STAGE_B3(0, 0, k2) STAGE_B3(0, 1, k2)
      BARRIER MFMA_PH1(2, af) BARRIER }
    { bf16x8 af[2]; DS_A1(0, 3, af) STAGE_B3(0, 2, k2) VMW3;
      BARRIER MFMA_PH1(3, af) BARRIER }
    { bf16x8 af[2]; DS_B1(1) DS_A1(1, 0, af) STAGE_A1(0, k2)
      BARRIER MFMA_PH1(0, af) BARRIER }
    { bf16x8 af[2]; DS_A1(1, 1, af)
      BARRIER MFMA_PH1(1, af) BARRIER }
    { bf16x8 af[2]; DS_A1(1, 2, af) STAGE_B3(1, 0, k3) STAGE_B3(1, 1, k3)
      BARRIER MFMA_PH1(2, af) BARRIER }
    { bf16x8 af[2]; DS_A1(1, 3, af) STAGE_B3(1, 2, k3) VMW3;
      BARRIER MFMA_PH1(3, af) BARRIER }
  }
  {  // peeled epilogue
    const int kA = ((NIT - 1) << 7) + 64;
    { bf16x8 af[2]; DS_B1(0) DS_A1(0, 0, af) STAGE_A1(1, kA)
      BARRIER MFMA_PH1(0, af) BARRIER }
    { bf16x8 af[2]; DS_A1(0, 1, af)
      BARRIER MFMA_PH1(1, af) BARRIER }
    { bf16x8 af[2]; DS_A1(0, 2, af)
      BARRIER MFMA_PH1(2, af) BARRIER }
    { bf16x8 af[2]; DS_A1(0, 3, af) VMW0;
      BARRIER MFMA_PH1(3, af) BARRIER }
    { bf16x8 af[2]; DS_B1(1) DS_A1(1, 0, af)
      BARRIER MFMA_PH1(0, af) BARRIER }
    { bf16x8 af[2]; DS_A1(1, 1, af)
      BARRIER MFMA_PH1(1, af) BARRIER }
    { bf16x8 af[2]; DS_A1(1, 2, af)
      BARRIER MFMA_PH1(2, af) BARRIER }
    { bf16x8 af[2]; DS_A1(1, 3, af)
      BARRIER MFMA_PH1(3, af) BARRIER }
  }

  float bv[3];
#pragma unroll
  for (int n = 0; n < 3; ++n) bv[n] = bias[z * sBias + n0 + wc * 48 + n * 16 + l15];
#pragma unroll
  for (int m = 0; m < 4; ++m) {
#pragma unroll
    for (int n = 0; n < 3; ++n) {
#pragma unroll
      for (int ri = 0; ri < 4; ++ri) {
        int row = m0 + wr * 64 + m * 16 + lhi * 4 + ri;
        int col = n0 + wc * 48 + n * 16 + l15;
        float v = acc[m][n][ri] + bv[n];
        size_t ci = (size_t)z * sC + (size_t)row * ldc + col;
        if (OUT_BF16) ((ushort_t*)Cp)[ci] = f2bf(v);
        else          ((float*)Cp)[ci]    = v;
      }
    }
  }
#undef STAGE_A1
#undef STAGE_B3
#undef DS_A1
#undef DS_B1
#undef MFMA_PH1
}

// ====== fused tail: Sp partials -> sred -> t_gemm -> ugcv, one kernel ======
// grid = 512 blocks x 256 thr; 3 device-scope grid barriers. LDS 18432 B.
__global__ __launch_bounds__(256) void tail_k(
    const ushort_t* __restrict__ kv, float* __restrict__ Sp,
    ushort_t* __restrict__ S, const float* __restrict__ wproj,
    ushort_t* __restrict__ Tt, const ushort_t* __restrict__ wqr,
    const float* __restrict__ bq, const float* __restrict__ bproj,
    ushort_t* __restrict__ Ut, float* __restrict__ cvec,
    unsigned* __restrict__ cnt) {
  __shared__ ushort_t sm[9216];  // union of per-phase layouts (18432 B)
  const int bid = blockIdx.x;
  const int tid = threadIdx.x;

  // ---- phase 1: Sp[chunk][bh][64][64] = K_c^T @ V_c, chunks of 512 rows ----
  if (bid < 192) {
    const int bh = bid % 24, chunk = bid / 24;
    const int b = bh / 12, h = bh % 12;
    const size_t base = (size_t)b * 4096 * 1536;
    const int koff = h * 64, voff = 768 + h * 64;
    const int nn = tid >> 3;
    const int dg = (tid & 7) * 8;
    const int w = tid >> 6, l15 = tid & 15, lhi = (tid & 63) >> 4;
    ushort_t* kt = sm;             // [64][34]
    ushort_t* vt = sm + 64 * 34;   // [64][34]
    f32x4 acc[4] = {};
    const int nbeg = chunk * 512;
    for (int n0 = nbeg; n0 < nbeg + 512; n0 += 32) {
      __syncthreads();
      size_t rowb = base + (size_t)(n0 + nn) * 1536;
      union { uint4 v; ushort_t s[8]; } uk, uv;
      uk.v = *(const uint4*)(kv + rowb + koff + dg);
      uv.v = *(const uint4*)(kv + rowb + voff + dg);
#pragma unroll
      for (int j = 0; j < 8; ++j) {
        kt[(dg + j) * 34 + nn] = uk.s[j];
        vt[(dg + j) * 34 + nn] = uv.s[j];
      }
      __syncthreads();
      bf16x8 af = *(const bf16x8*)&kt[(w * 16 + l15) * 34 + lhi * 8];
#pragma unroll
      for (int t = 0; t < 4; ++t) {
        bf16x8 bf = *(const bf16x8*)&vt[(t * 16 + l15) * 34 + lhi * 8];
        acc[t] = mfma16(af, bf, acc[t]);
      }
    }
#pragma unroll
    for (int t = 0; t < 4; ++t)
#pragma unroll
      for (int r = 0; r < 4; ++r)
        Sp[((size_t)chunk * 24 + bh) * 4096 +
           (w * 16 + lhi * 4 + r) * 64 + t * 16 + l15] = acc[t][r];
  }
  gsync(cnt, 512);

  // ---- phase 2: S = bf16(0.125 * sum_chunk Sp) ----
  if (bid < 384) {
    int i = bid * 256 + tid;
    float a = 0.f;
#pragma unroll
    for (int c = 0; c < 8; ++c) a += Sp[(size_t)c * 98304 + i];
    S[i] = f2bf(a * 0.125f);
  }
  gsync(cnt, 1024);

  // ---- phase 3: Tt[b][c][h*64+d1] = sum_d2 S[bh][d1][d2]*wproj[h*64+d2][c] --
  if (bid < 288) {
    const int n0 = (bid % 12) * 64;
    const int bh = bid / 12;
    const int b = bh / 12, h = bh % 12;
    ushort_t* a_lds = sm;              // [64][66]
    ushort_t* b_lds = sm + 64 * 66;    // [64][66]
    {
      int m = tid >> 2, kg = tid & 3;
#pragma unroll
      for (int j = 0; j < 16; ++j) {
        int k = kg * 16 + j;
        a_lds[m * 66 + k] = S[(size_t)bh * 4096 + m * 64 + k];
      }
      int n = tid & 63, kg2 = tid >> 6;
#pragma unroll
      for (int j = 0; j < 16; ++j) {
        int k = kg2 * 16 + j;
        b_lds[n * 66 + k] = f2bf(wproj[(size_t)(h * 64 + k) * 768 + n0 + n]);
      }
    }
    __syncthreads();
    const int w = tid >> 6, l = tid & 63, l15 = l & 15, lhi = l >> 4;
    f32x4 acc[4] = {};
#pragma unroll
    for (int kk = 0; kk < 64; kk += 32) {
      bf16x8 af = *(const bf16x8*)&a_lds[(w * 16 + l15) * 66 + kk + lhi * 8];
#pragma unroll
      for (int t = 0; t < 4; ++t) {
        bf16x8 bf = *(const bf16x8*)&b_lds[(t * 16 + l15) * 66 + kk + lhi * 8];
        acc[t] = mfma16(af, bf, acc[t]);
      }
    }
#pragma unroll
    for (int t = 0; t < 4; ++t)
#pragma unroll
      for (int r = 0; r < 4; ++r) {
        int row = h * 64 + w * 16 + lhi * 4 + r;
        int col = n0 + t * 16 + l15;
        Tt[(size_t)b * 768 * 768 + (size_t)col * 768 + row] = f2bf(acc[t][r]);
      }
  }
  gsync(cnt, 1536);

  // ---- phase 4: Ut = (Wq @ T)^T (288 blocks); cvec rows (224 blocks) ----
  if (bid < 288) {
    const int n0 = (bid % 12) * 64, m0 = ((bid / 12) % 12) * 64;
    const long long z = bid / 144;
    const ushort_t* Ab = Tt + z * 768 * 768;
    ushort_t* a_lds = sm;              // [64][72]
    ushort_t* b_lds = sm + 64 * 72;    // [64][72]
    const int w = tid >> 6, l = tid & 63, l15 = l & 15, lhi = l >> 4;
    const int r2 = tid >> 3, kc = (tid & 7) * 8;
    f32x4 acc[4] = {};
    for (int k0 = 0; k0 < 768; k0 += 64) {
      __syncthreads();
      *(uint4*)&a_lds[r2 * 72 + kc]        = *(const uint4*)(Ab + (size_t)(m0 + r2) * 768 + k0 + kc);
      *(uint4*)&a_lds[(r2 + 32) * 72 + kc] = *(const uint4*)(Ab + (size_t)(m0 + r2 + 32) * 768 + k0 + kc);
      *(uint4*)&b_lds[r2 * 72 + kc]        = *(const uint4*)(wqr + (size_t)(n0 + r2) * 768 + k0 + kc);
      *(uint4*)&b_lds[(r2 + 32) * 72 + kc] = *(const uint4*)(wqr + (size_t)(n0 + r2 + 32) * 768 + k0 + kc);
      __syncthreads();
#pragma unroll
      for (int kk = 0; kk < 2; ++kk) {
        bf16x8 af = *(const bf16x8*)&a_lds[(w * 16 + l15) * 72 + kk * 32 + lhi * 8];
#pragma unroll
        for (int t = 0; t < 4; ++t) {
          bf16x8 bf = *(const bf16x8*)&b_lds[(t * 16 + l15) * 72 + kk * 32 + lhi * 8];
          acc[t] = mfma16(af, bf, acc[t]);
        }
      }
    }
#pragma unroll
    for (int t = 0; t < 4; ++t)
#pragma unroll
      for (int r = 0; r < 4; ++r) {
        int row = m0 + w * 16 + lhi * 4 + r, col = n0 + t * 16 + l15;
        Ut[z * 768 * 768 + (size_t)row * 768 + col] = f2bf(acc[t][r]);
      }
  } else {
    const int lane = tid & 63;
    for (int row = (bid - 288) * 4 + (tid >> 6); row < 1536; row += 224 * 4) {
      const ushort_t* r = Tt + (size_t)row * 768;
      float acc = 0.f;
#pragma unroll
      for (int k0 = 0; k0 < 768; k0 += 256) {
        int k = k0 + lane * 4;
        float4 b4 = *(const float4*)(bq + k);
        union { unsigned long long v; ushort_t s[4]; } u;
        u.v = *(const unsigned long long*)(r + k);
        acc += b4.x * bf2f(u.s[0]) + b4.y * bf2f(u.s[1]) +
               b4.z * bf2f(u.s[2]) + b4.w * bf2f(u.s[3]);
      }
#pragma unroll
      for (int off = 32; off > 0; off >>= 1) acc += __shfl_down(acc, off, 64);
      if (lane == 0) cvec[row] = acc + bproj[row % 768];
    }
  }
}

extern "C" void kernel_launch(void* const* d_in, const int* in_sizes, int n_in,
                              void* d_out, int out_size, void* d_ws, size_t ws_size,
                              hipStream_t stream) {
  const float* x      = (const float*)d_in[0];
  const float* w_qkv  = (const float*)d_in[1];
  const float* b_qkv  = (const float*)d_in[2];
  const float* w_proj = (const float*)d_in[3];
  const float* b_proj = (const float*)d_in[4];
  float* out = (float*)d_out;

  char* ws = (char*)d_ws;
  ushort_t* xb   = (ushort_t*)ws;                    // 12,582,912 B
  ushort_t* wqt  = (ushort_t*)(ws + 12582912);       //  3,538,944 B (rows 768+ used)
  ushort_t* wqr  = (ushort_t*)(ws + 16121856);       //  1,179,648 B
  ushort_t* Ut   = (ushort_t*)(ws + 17301504);       //  2,359,296 B
  ushort_t* kv   = (ushort_t*)(ws + 19660800);       // 25,165,824 B
  float*    Sp   = (float*)   (ws + 44826624);       //  3,145,728 B (8 chunks)
  ushort_t* S    = (ushort_t*)(ws + 51118080);       //    196,608 B
  ushort_t* Tt   = (ushort_t*)(ws + 51314688);       //  2,359,296 B
  float*    cvec = (float*)   (ws + 53673984);       //      6,144 B
  unsigned* cnt  = (unsigned*)(ws + 53680128);       //          4 B

  // 0) all converts fused: x->xb, KV-cols->wqt^T, Wq rows->wqr
  conv_all_k<<<dim3(3648), 256, 0, stream>>>(x, w_qkv, xb, wqt, wqr);
  // 1) kv = x @ w_kv + b_kv -> bf16 [8192][1536]  (32 m x 8 n = 256 blocks)
  g256x192_k<true><<<dim3(256, 1), 512, 0, stream>>>(
      xb, 768, 0LL, wqt + 768 * 768, 768, 0LL, b_qkv + 768, 0LL,
      kv, 1536, 0LL, 768, 8);
  // 2-5) fused tail: Sp partials -> reduce -> T -> U/cvec (grid barriers)
  hipMemsetAsync(cnt, 0, 4, stream);
  tail_k<<<dim3(512), 256, 0, stream>>>(kv, Sp, S, w_proj, Tt, wqr,
                                        b_qkv, b_proj, Ut, cvec, cnt);
  // 6) out[b] = x[b] @ U[b] + cvec[b]  (32 m x 4 n per z, z=2 -> 256 blocks)
  g128x192_k<false><<<dim3(128, 2), 512, 0, stream>>>(
      xb, 768, 4096LL * 768, Ut, 768, 768LL * 768, cvec, 768LL,
      out, 768, 4096LL * 768, 768, 4);
}

// Round 13
// 77.941 us; speedup vs baseline: 3.5963x; 3.5963x over previous
//
#include <hip/hip_runtime.h>

typedef unsigned short ushort_t;
typedef __bf16 bf16_t;
typedef __attribute__((ext_vector_type(8))) bf16_t bf16x8;
typedef __attribute__((ext_vector_type(4))) float f32x4;

__device__ __forceinline__ ushort_t f2bf(float f) {
  unsigned int u = __builtin_bit_cast(unsigned int, f);
  u += 0x7FFFu + ((u >> 16) & 1u);
  return (ushort_t)(u >> 16);
}

__device__ __forceinline__ float bf2f(ushort_t s) {
  return __builtin_bit_cast(float, (unsigned int)s << 16);
}

__device__ __forceinline__ f32x4 mfma16(bf16x8 a, bf16x8 b, f32x4 c) {
  return __builtin_amdgcn_mfma_f32_16x16x32_bf16(a, b, c, 0, 0, 0);
}

__device__ __forceinline__ void async_copy16(const void* g, void* l) {
  __builtin_amdgcn_global_load_lds(
      (const __attribute__((address_space(1))) unsigned int*)g,
      (__attribute__((address_space(3))) unsigned int*)l,
      16, 0, 0);
}

#define BARRIER { __builtin_amdgcn_s_barrier(); asm volatile("" ::: "memory"); }
#define VMW3 asm volatile("s_waitcnt vmcnt(3)" ::: "memory")
#define VMW0 asm volatile("s_waitcnt vmcnt(0)" ::: "memory")

// ====== fused converts: x->bf16, w_qkv KV-cols -> wqt^T, Wq rows -> wqr ======
__global__ __launch_bounds__(256) void conv_all_k(const float* __restrict__ x,
                                                  const float* __restrict__ w,
                                                  ushort_t* __restrict__ xb,
                                                  ushort_t* __restrict__ wqt,
                                                  ushort_t* __restrict__ wqr) {
  __shared__ float lds[64][65];
  const int bid = blockIdx.x;
  const int tid = threadIdx.x;
  if (bid < 3072) {                      // x -> bf16
    int i = (bid * 256 + tid) * 8;
    float4 f0 = *(const float4*)(x + i);
    float4 f1 = *(const float4*)(x + i + 4);
    union { ushort_t s[8]; uint4 v; } u;
    u.s[0] = f2bf(f0.x); u.s[1] = f2bf(f0.y); u.s[2] = f2bf(f0.z); u.s[3] = f2bf(f0.w);
    u.s[4] = f2bf(f1.x); u.s[5] = f2bf(f1.y); u.s[6] = f2bf(f1.z); u.s[7] = f2bf(f1.w);
    *(uint4*)(xb + i) = u.v;
  } else if (bid < 3360) {               // K,V cols transpose: 24 x 12 tiles
    const int ii = bid - 3072;
    const int n0 = 768 + (ii % 24) * 64;
    const int k0 = (ii / 24) * 64;
#pragma unroll
    for (int q = 0; q < 16; ++q) {
      int lin = tid + q * 256;
      int i = lin >> 6, j = lin & 63;
      lds[i][j] = w[(size_t)(k0 + i) * 2304 + n0 + j];
    }
    __syncthreads();
#pragma unroll
    for (int q = 0; q < 16; ++q) {
      int lin = tid + q * 256;
      int jj = lin >> 6, kk = lin & 63;
      wqt[(size_t)(n0 + jj) * 768 + k0 + kk] = f2bf(lds[kk][jj]);
    }
  } else {                               // Wq rows (k-contig): 288 blocks
    int i = ((bid - 3360) * 256 + tid) * 8;
    int row = i / 768, col = i % 768;
    const float* src = w + (size_t)row * 2304 + col;
    float4 f0 = *(const float4*)src;
    float4 f1 = *(const float4*)(src + 4);
    union { ushort_t s[8]; uint4 v; } u;
    u.s[0] = f2bf(f0.x); u.s[1] = f2bf(f0.y); u.s[2] = f2bf(f0.z); u.s[3] = f2bf(f0.w);
    u.s[4] = f2bf(f1.x); u.s[5] = f2bf(f1.y); u.s[6] = f2bf(f1.z); u.s[7] = f2bf(f1.w);
    *(uint4*)(wqr + i) = u.v;
  }
}

// =============== 256x192 8-phase GEMM (BN=192, 112 KiB LDS) ===============
// C[z] = A[z] @ Bt[z]^T + bias[z]. K = 128*NIT, NIT >= 2. grid.x % 8 == 0.
template <bool OUT_BF16>
__global__ __launch_bounds__(512, 2) void g256x192_k(
    const ushort_t* __restrict__ A, int lda, long long sA,
    const ushort_t* __restrict__ Bt, int ldb, long long sB,
    const float* __restrict__ bias, long long sBias,
    void* __restrict__ Cp, int ldc, long long sC,
    int K, int ntiles) {
  __shared__ char smem[114688];  // 2 x (A 32K + B 24K)
  const int tid = threadIdx.x;
  const int lane = tid & 63;
  const int wid = tid >> 6;
  const int l15 = lane & 15, lhi = lane >> 4;
  const int wr = wid >> 2, wc = wid & 3;
  const int sx = l15 & 7;

  const int nwg = gridDim.x;
  const int q = nwg >> 3;
  const int swz = (blockIdx.x & 7) * q + (blockIdx.x >> 3);
  const int mt = swz / ntiles, nt = swz % ntiles;
  const int m0 = mt << 8, n0 = nt * 192;
  const long long z = blockIdx.y;

  const ushort_t* Ab = A + z * sA;
  const ushort_t* Bb = Bt + z * sB;

  const int r0 = tid >> 3;
  const int sg = tid & 7;
  const int soff = (sg ^ (r0 & 7)) << 4;

#define STAGE_A(BUF, H, K0)                                                      \
  { const char* g0 = (const char*)(Ab + (size_t)(m0 + (H)*128 + r0) * lda + (K0)) + soff;      \
    const char* g1 = (const char*)(Ab + (size_t)(m0 + (H)*128 + r0 + 64) * lda + (K0)) + soff; \
    char* lb = smem + (BUF)*57344 + (H)*16384;                                   \
    async_copy16(g0, lb + tid * 16);                                             \
    async_copy16(g1, lb + 8192 + tid * 16); }

#define STAGE_B3(BUF, J, K0)                                                     \
  { const char* g0 = (const char*)(Bb + (size_t)(n0 + (J)*64 + r0) * ldb + (K0)) + soff;       \
    async_copy16(g0, smem + (BUF)*57344 + 32768 + (J)*8192 + tid * 16); }

  const int aBase = wr * 16384 + l15 * 128;
  const int bBase = 32768 + (wc * 48 + l15) * 128;
  const int sk0 = ((lhi ^ sx) << 4);
  const int sk1 = (((4 + lhi) ^ sx) << 4);

  f32x4 acc[8][3] = {};
  bf16x8 bfr[3][2];

#define DS_A(BUF, MPAIR, AF)                                                     \
  _Pragma("unroll") for (int mm = 0; mm < 2; ++mm) {                             \
    AF[mm][0] = *(const bf16x8*)(smem + (BUF)*57344 + aBase + ((MPAIR)*2+mm)*2048 + sk0); \
    AF[mm][1] = *(const bf16x8*)(smem + (BUF)*57344 + aBase + ((MPAIR)*2+mm)*2048 + sk1); }

#define DS_B(BUF)                                                                \
  _Pragma("unroll") for (int n = 0; n < 3; ++n) {                                \
    bfr[n][0] = *(const bf16x8*)(smem + (BUF)*57344 + bBase + n*2048 + sk0);     \
    bfr[n][1] = *(const bf16x8*)(smem + (BUF)*57344 + bBase + n*2048 + sk1); }

#define MFMA_PH(MPAIR, AF)                                                       \
  __builtin_amdgcn_s_setprio(1);                                                 \
  _Pragma("unroll") for (int mm = 0; mm < 2; ++mm)                               \
    _Pragma("unroll") for (int n = 0; n < 3; ++n) {                              \
      acc[(MPAIR)*2+mm][n] = mfma16(AF[mm][0], bfr[n][0], acc[(MPAIR)*2+mm][n]); \
      acc[(MPAIR)*2+mm][n] = mfma16(AF[mm][1], bfr[n][1], acc[(MPAIR)*2+mm][n]); } \
  __builtin_amdgcn_s_setprio(0);

  STAGE_A(0, 0, 0) STAGE_A(0, 1, 0)
  STAGE_B3(0, 0, 0) STAGE_B3(0, 1, 0) STAGE_B3(0, 2, 0)
  STAGE_B3(1, 0, 64) STAGE_B3(1, 1, 64) STAGE_B3(1, 2, 64)
  VMW3;
  BARRIER

  const int NIT = K >> 7;
#pragma unroll 1
  for (int it = 0; it < NIT - 1; ++it) {
    const int kA = (it << 7) + 64;
    const int k2 = (it << 7) + 128;
    const int k3 = (it << 7) + 192;
    { bf16x8 af[2][2]; DS_B(0) DS_A(0, 0, af) STAGE_A(1, 0, kA)
      BARRIER MFMA_PH(0, af) BARRIER }
    { bf16x8 af[2][2]; DS_A(0, 1, af) STAGE_A(1, 1, kA)
      BARRIER MFMA_PH(1, af) BARRIER }
    { bf16x8 af[2][2]; DS_A(0, 2, af) STAGE_B3(0, 0, k2) STAGE_B3(0, 1, k2)
      BARRIER MFMA_PH(2, af) BARRIER }
    { bf16x8 af[2][2]; DS_A(0, 3, af) STAGE_B3(0, 2, k2) VMW3;
      BARRIER MFMA_PH(3, af) BARRIER }
    { bf16x8 af[2][2]; DS_B(1) DS_A(1, 0, af) STAGE_A(0, 0, k2)
      BARRIER MFMA_PH(0, af) BARRIER }
    { bf16x8 af[2][2]; DS_A(1, 1, af) STAGE_A(0, 1, k2)
      BARRIER MFMA_PH(1, af) BARRIER }
    { bf16x8 af[2][2]; DS_A(1, 2, af) STAGE_B3(1, 0, k3) STAGE_B3(1, 1, k3)
      BARRIER MFMA_PH(2, af) BARRIER }
    { bf16x8 af[2][2]; DS_A(1, 3, af) STAGE_B3(1, 2, k3) VMW3;
      BARRIER MFMA_PH(3, af) BARRIER }
  }
  {  // peeled epilogue: only A(buf1)@kA staged; VMW0 at ph4
    const int kA = ((NIT - 1) << 7) + 64;
    { bf16x8 af[2][2]; DS_B(0) DS_A(0, 0, af) STAGE_A(1, 0, kA)
      BARRIER MFMA_PH(0, af) BARRIER }
    { bf16x8 af[2][2]; DS_A(0, 1, af) STAGE_A(1, 1, kA)
      BARRIER MFMA_PH(1, af) BARRIER }
    { bf16x8 af[2][2]; DS_A(0, 2, af)
      BARRIER MFMA_PH(2, af) BARRIER }
    { bf16x8 af[2][2]; DS_A(0, 3, af) VMW0;
      BARRIER MFMA_PH(3, af) BARRIER }
    { bf16x8 af[2][2]; DS_B(1) DS_A(1, 0, af)
      BARRIER MFMA_PH(0, af) BARRIER }
    { bf16x8 af[2][2]; DS_A(1, 1, af)
      BARRIER MFMA_PH(1, af) BARRIER }
    { bf16x8 af[2][2]; DS_A(1, 2, af)
      BARRIER MFMA_PH(2, af) BARRIER }
    { bf16x8 af[2][2]; DS_A(1, 3, af)
      BARRIER MFMA_PH(3, af) BARRIER }
  }

  float bv[3];
#pragma unroll
  for (int n = 0; n < 3; ++n) bv[n] = bias[z * sBias + n0 + wc * 48 + n * 16 + l15];
#pragma unroll
  for (int m = 0; m < 8; ++m) {
#pragma unroll
    for (int n = 0; n < 3; ++n) {
#pragma unroll
      for (int ri = 0; ri < 4; ++ri) {
        int row = m0 + wr * 128 + m * 16 + lhi * 4 + ri;
        int col = n0 + wc * 48 + n * 16 + l15;
        float v = acc[m][n][ri] + bv[n];
        size_t ci = (size_t)z * sC + (size_t)row * ldc + col;
        if (OUT_BF16) ((ushort_t*)Cp)[ci] = f2bf(v);
        else          ((float*)Cp)[ci]    = v;
      }
    }
  }
#undef STAGE_A
#undef STAGE_B3
#undef DS_A
#undef DS_B
#undef MFMA_PH
}

// =============== 128x192 8-phase GEMM (BM=128, 80 KiB LDS) ===============
template <bool OUT_BF16>
__global__ __launch_bounds__(512, 2) void g128x192_k(
    const ushort_t* __restrict__ A, int lda, long long sA,
    const ushort_t* __restrict__ Bt, int ldb, long long sB,
    const float* __restrict__ bias, long long sBias,
    void* __restrict__ Cp, int ldc, long long sC,
    int K, int ntiles) {
  __shared__ char smem[81920];  // 2 x (A 16K + B 24K)
  const int tid = threadIdx.x;
  const int lane = tid & 63;
  const int wid = tid >> 6;
  const int l15 = lane & 15, lhi = lane >> 4;
  const int wr = wid >> 2, wc = wid & 3;
  const int sx = l15 & 7;

  const int nwg = gridDim.x;
  const int q = nwg >> 3;
  const int swz = (blockIdx.x & 7) * q + (blockIdx.x >> 3);
  const int mt = swz / ntiles, nt = swz % ntiles;
  const int m0 = mt << 7, n0 = nt * 192;
  const long long z = blockIdx.y;

  const ushort_t* Ab = A + z * sA;
  const ushort_t* Bb = Bt + z * sB;

  const int r0 = tid >> 3;
  const int sg = tid & 7;
  const int soff = (sg ^ (r0 & 7)) << 4;

#define STAGE_A1(BUF, K0)                                                        \
  { const char* g0 = (const char*)(Ab + (size_t)(m0 + r0) * lda + (K0)) + soff;               \
    const char* g1 = (const char*)(Ab + (size_t)(m0 + r0 + 64) * lda + (K0)) + soff;          \
    char* lb = smem + (BUF)*40960;                                               \
    async_copy16(g0, lb + tid * 16);                                             \
    async_copy16(g1, lb + 8192 + tid * 16); }

#define STAGE_B3(BUF, J, K0)                                                     \
  { const char* g0 = (const char*)(Bb + (size_t)(n0 + (J)*64 + r0) * ldb + (K0)) + soff;       \
    async_copy16(g0, smem + (BUF)*40960 + 16384 + (J)*8192 + tid * 16); }

  const int aBase = wr * 8192 + l15 * 128;
  const int bBase = 16384 + (wc * 48 + l15) * 128;
  const int sk0 = ((lhi ^ sx) << 4);
  const int sk1 = (((4 + lhi) ^ sx) << 4);

  f32x4 acc[4][3] = {};
  bf16x8 bfr[3][2];

#define DS_A1(BUF, M, AF)                                                        \
  { AF[0] = *(const bf16x8*)(smem + (BUF)*40960 + aBase + (M)*2048 + sk0);       \
    AF[1] = *(const bf16x8*)(smem + (BUF)*40960 + aBase + (M)*2048 + sk1); }

#define DS_B1(BUF)                                                               \
  _Pragma("unroll") for (int n = 0; n < 3; ++n) {                                \
    bfr[n][0] = *(const bf16x8*)(smem + (BUF)*40960 + bBase + n*2048 + sk0);     \
    bfr[n][1] = *(const bf16x8*)(smem + (BUF)*40960 + bBase + n*2048 + sk1); }

#define MFMA_PH1(M, AF)                                                          \
  __builtin_amdgcn_s_setprio(1);                                                 \
  _Pragma("unroll") for (int n = 0; n < 3; ++n) {                                \
    acc[M][n] = mfma16(AF[0], bfr[n][0], acc[M][n]);                             \
    acc[M][n] = mfma16(AF[1], bfr[n][1], acc[M][n]); }                           \
  __builtin_amdgcn_s_setprio(0);

  STAGE_A1(0, 0)
  STAGE_B3(0, 0, 0) STAGE_B3(0, 1, 0) STAGE_B3(0, 2, 0)
  STAGE_B3(1, 0, 64) STAGE_B3(1, 1, 64) STAGE_B3(1, 2, 64)
  VMW3;
  BARRIER

  const int NIT = K >> 7;
#pragma unroll 1
  for (int it = 0; it < NIT - 1; ++it) {
    const int kA = (it << 7) + 64;
    const int k2 = (it << 7) + 128;
    const int k3 = (it << 7) + 192;
    { bf16x8 af[2]; DS_B1(0) DS_A1(0, 0, af) STAGE_A1(1, kA)
      BARRIER MFMA_PH1(0, af) BARRIER }
    { bf16x8 af[2]; DS_A1(0, 1, af)
      BARRIER MFMA_PH1(1, af) BARRIER }
    { bf16x8 af[2]; DS_A1(0, 2, af) STAGE_B3(0, 0, k2) STAGE_B3(0, 1, k2)
      BARRIER MFMA_PH1(2, af) BARRIER }
    { bf16x8 af[2]; DS_A1(0, 3, af) STAGE_B3(0, 2, k2) VMW3;
      BARRIER MFMA_PH1(3, af) BARRIER }
    { bf16x8 af[2]; DS_B1(1) DS_A1(1, 0, af) STAGE_A1(0, k2)
      BARRIER MFMA_PH1(0, af) BARRIER }
    { bf16x8 af[2]; DS_A1(1, 1, af)
      BARRIER MFMA_PH1(1, af) BARRIER }
    { bf16x8 af[2]; DS_A1(1, 2, af) STAGE_B3(1, 0, k3) STAGE_B3(1, 1, k3)
      BARRIER MFMA_PH1(2, af) BARRIER }
    { bf16x8 af[2]; DS_A1(1, 3, af) STAGE_B3(1, 2, k3) VMW3;
      BARRIER MFMA_PH1(3, af) BARRIER }
  }
  {  // peeled epilogue
    const int kA = ((NIT - 1) << 7) + 64;
    { bf16x8 af[2]; DS_B1(0) DS_A1(0, 0, af) STAGE_A1(1, kA)
      BARRIER MFMA_PH1(0, af) BARRIER }
    { bf16x8 af[2]; DS_A1(0, 1, af)
      BARRIER MFMA_PH1(1, af) BARRIER }
    { bf16x8 af[2]; DS_A1(0, 2, af)
      BARRIER MFMA_PH1(2, af) BARRIER }
    { bf16x8 af[2]; DS_A1(0, 3, af) VMW0;
      BARRIER MFMA_PH1(3, af) BARRIER }
    { bf16x8 af[2]; DS_B1(1) DS_A1(1, 0, af)
      BARRIER MFMA_PH1(0, af) BARRIER }
    { bf16x8 af[2]; DS_A1(1, 1, af)
      BARRIER MFMA_PH1(1, af) BARRIER }
    { bf16x8 af[2]; DS_A1(1, 2, af)
      BARRIER MFMA_PH1(2, af) BARRIER }
    { bf16x8 af[2]; DS_A1(1, 3, af)
      BARRIER MFMA_PH1(3, af) BARRIER }
  }

  float bv[3];
#pragma unroll
  for (int n = 0; n < 3; ++n) bv[n] = bias[z * sBias + n0 + wc * 48 + n * 16 + l15];
#pragma unroll
  for (int m = 0; m < 4; ++m) {
#pragma unroll
    for (int n = 0; n < 3; ++n) {
#pragma unroll
      for (int ri = 0; ri < 4; ++ri) {
        int row = m0 + wr * 64 + m * 16 + lhi * 4 + ri;
        int col = n0 + wc * 48 + n * 16 + l15;
        float v = acc[m][n][ri] + bv[n];
        size_t ci = (size_t)z * sC + (size_t)row * ldc + col;
        if (OUT_BF16) ((ushort_t*)Cp)[ci] = f2bf(v);
        else          ((float*)Cp)[ci]    = v;
      }
    }
  }
#undef STAGE_A1
#undef STAGE_B3
#undef DS_A1
#undef DS_B1
#undef MFMA_PH1
}

// S partial: per (b,h), n-chunk of 256: Sp[chunk][bh][64][64] = K_c^T @ V_c
// VECTORIZED staging: each thread does one uint4 load per operand per step.
__global__ __launch_bounds__(256) void kv_k(const ushort_t* __restrict__ kv,
                                            float* __restrict__ Sp) {
  __shared__ ushort_t kt[64][34];
  __shared__ ushort_t vt[64][34];
  const int bh = blockIdx.x;
  const int chunk = blockIdx.y;
  const int b = bh / 12, h = bh % 12;
  const size_t base = (size_t)b * 4096 * 1536;
  const int koff = h * 64, voff = 768 + h * 64;
  const int tid = threadIdx.x;
  const int nn = tid >> 3;        // 0..31 (row within 32-row step)
  const int dg = (tid & 7) * 8;   // 0,8,...,56 (d-group of 8)
  const int w = tid >> 6, l = tid & 63, l15 = l & 15, lhi = l >> 4;

  f32x4 acc[4] = {};
  const int nbeg = chunk * 256;
  for (int n0 = nbeg; n0 < nbeg + 256; n0 += 32) {
    __syncthreads();
    size_t rowb = base + (size_t)(n0 + nn) * 1536;
    union { uint4 v; ushort_t s[8]; } uk, uv;
    uk.v = *(const uint4*)(kv + rowb + koff + dg);
    uv.v = *(const uint4*)(kv + rowb + voff + dg);
#pragma unroll
    for (int j = 0; j < 8; ++j) {
      kt[dg + j][nn] = uk.s[j];
      vt[dg + j][nn] = uv.s[j];
    }
    __syncthreads();
    bf16x8 af = *(const bf16x8*)&kt[w * 16 + l15][lhi * 8];
#pragma unroll
    for (int t = 0; t < 4; ++t) {
      bf16x8 bf = *(const bf16x8*)&vt[t * 16 + l15][lhi * 8];
      acc[t] = mfma16(af, bf, acc[t]);
    }
  }
#pragma unroll
  for (int t = 0; t < 4; ++t) {
#pragma unroll
    for (int r = 0; r < 4; ++r) {
      int d1 = w * 16 + lhi * 4 + r;
      int d2 = t * 16 + l15;
      Sp[((size_t)chunk * 24 + bh) * 4096 + d1 * 64 + d2] = acc[t][r];
    }
  }
}

__global__ __launch_bounds__(256) void sred_k(const float* __restrict__ Sp,
                                              ushort_t* __restrict__ S) {
  int i = blockIdx.x * 256 + threadIdx.x;
  float a = 0.f;
#pragma unroll
  for (int c = 0; c < 16; ++c) a += Sp[(size_t)c * 98304 + i];
  S[i] = f2bf(a * 0.125f);
}

// Tt[b][c][h*64+d1] = sum_d2 S[bh][d1][d2] * w_proj[h*64+d2][c]
__global__ __launch_bounds__(256) void t_gemm_k(const ushort_t* __restrict__ S,
                                                const float* __restrict__ wproj,
                                                ushort_t* __restrict__ Tt) {
  __shared__ ushort_t a_lds[64][66];
  __shared__ ushort_t b_lds[64][66];
  const int n0 = blockIdx.x * 64;
  const int bh = blockIdx.y;
  const int b = bh / 12, h = bh % 12;
  const int tid = threadIdx.x;
  {
    int m = tid >> 2, kg = tid & 3;
#pragma unroll
    for (int j = 0; j < 16; ++j) {
      int k = kg * 16 + j;
      a_lds[m][k] = S[(size_t)bh * 4096 + m * 64 + k];
    }
    int n = tid & 63, kg2 = tid >> 6;
#pragma unroll
    for (int j = 0; j < 16; ++j) {
      int k = kg2 * 16 + j;
      b_lds[n][k] = f2bf(wproj[(size_t)(h * 64 + k) * 768 + n0 + n]);
    }
  }
  __syncthreads();
  const int w = tid >> 6, l = tid & 63, l15 = l & 15, lhi = l >> 4;
  f32x4 acc[4] = {};
#pragma unroll
  for (int kk = 0; kk < 64; kk += 32) {
    bf16x8 af = *(const bf16x8*)&a_lds[w * 16 + l15][kk + lhi * 8];
#pragma unroll
    for (int t = 0; t < 4; ++t) {
      bf16x8 bf = *(const bf16x8*)&b_lds[t * 16 + l15][kk + lhi * 8];
      acc[t] = mfma16(af, bf, acc[t]);
    }
  }
#pragma unroll
  for (int t = 0; t < 4; ++t) {
#pragma unroll
    for (int r = 0; r < 4; ++r) {
      int row = h * 64 + w * 16 + lhi * 4 + r;
      int col = n0 + t * 16 + l15;
      Tt[(size_t)b * 768 * 768 + (size_t)col * 768 + row] = f2bf(acc[t][r]);
    }
  }
}

// fused: blocks [0,288): Ut = (Wq @ T)^T tiles; blocks [288,672): cvec rows
__global__ __launch_bounds__(256) void ugcv_k(const ushort_t* __restrict__ Tt,
                                              const ushort_t* __restrict__ wqr,
                                              const float* __restrict__ bq,
                                              const float* __restrict__ bproj,
                                              ushort_t* __restrict__ Ut,
                                              float* __restrict__ cvec) {
  __shared__ ushort_t a_lds[64][72];
  __shared__ ushort_t b_lds[64][72];
  const int bid = blockIdx.x;
  const int tid = threadIdx.x;
  if (bid < 288) {
    const int n0 = (bid % 12) * 64, m0 = ((bid / 12) % 12) * 64;
    const long long z = bid / 144;
    const ushort_t* Ab = Tt + z * 768 * 768;
    const int w = tid >> 6, l = tid & 63, l15 = l & 15, lhi = l >> 4;
    const int r2 = tid >> 3, kc = (tid & 7) * 8;
    f32x4 acc[4] = {};
    for (int k0 = 0; k0 < 768; k0 += 64) {
      __syncthreads();
      *(uint4*)&a_lds[r2][kc]      = *(const uint4*)(Ab + (size_t)(m0 + r2) * 768 + k0 + kc);
      *(uint4*)&a_lds[r2 + 32][kc] = *(const uint4*)(Ab + (size_t)(m0 + r2 + 32) * 768 + k0 + kc);
      *(uint4*)&b_lds[r2][kc]      = *(const uint4*)(wqr + (size_t)(n0 + r2) * 768 + k0 + kc);
      *(uint4*)&b_lds[r2 + 32][kc] = *(const uint4*)(wqr + (size_t)(n0 + r2 + 32) * 768 + k0 + kc);
      __syncthreads();
#pragma unroll
      for (int kk = 0; kk < 2; ++kk) {
        bf16x8 af = *(const bf16x8*)&a_lds[w * 16 + l15][kk * 32 + lhi * 8];
#pragma unroll
        for (int t = 0; t < 4; ++t) {
          bf16x8 bf = *(const bf16x8*)&b_lds[t * 16 + l15][kk * 32 + lhi * 8];
          acc[t] = mfma16(af, bf, acc[t]);
        }
      }
    }
#pragma unroll
    for (int t = 0; t < 4; ++t) {
#pragma unroll
      for (int r = 0; r < 4; ++r) {
        int row = m0 + w * 16 + lhi * 4 + r, col = n0 + t * 16 + l15;
        Ut[z * 768 * 768 + (size_t)row * 768 + col] = f2bf(acc[t][r]);
      }
    }
  } else {
    const int row = (bid - 288) * 4 + (tid >> 6);
    const int lane = tid & 63;
    const ushort_t* r = Tt + (size_t)row * 768;
    float acc = 0.f;
#pragma unroll
    for (int k0 = 0; k0 < 768; k0 += 256) {
      int k = k0 + lane * 4;
      float4 b4 = *(const float4*)(bq + k);
      union { unsigned long long v; ushort_t s[4]; } u;
      u.v = *(const unsigned long long*)(r + k);
      acc += b4.x * bf2f(u.s[0]) + b4.y * bf2f(u.s[1]) +
             b4.z * bf2f(u.s[2]) + b4.w * bf2f(u.s[3]);
    }
#pragma unroll
    for (int off = 32; off > 0; off >>= 1) acc += __shfl_down(acc, off, 64);
    if (lane == 0) cvec[row] = acc + bproj[row % 768];
  }
}

extern "C" void kernel_launch(void* const* d_in, const int* in_sizes, int n_in,
                              void* d_out, int out_size, void* d_ws, size_t ws_size,
                              hipStream_t stream) {
  const float* x      = (const float*)d_in[0];
  const float* w_qkv  = (const float*)d_in[1];
  const float* b_qkv  = (const float*)d_in[2];
  const float* w_proj = (const float*)d_in[3];
  const float* b_proj = (const float*)d_in[4];
  float* out = (float*)d_out;

  char* ws = (char*)d_ws;
  ushort_t* xb   = (ushort_t*)ws;                    // 12,582,912 B
  ushort_t* wqt  = (ushort_t*)(ws + 12582912);       //  3,538,944 B (rows 768+ used)
  ushort_t* wqr  = (ushort_t*)(ws + 16121856);       //  1,179,648 B
  ushort_t* Ut   = (ushort_t*)(ws + 17301504);       //  2,359,296 B
  ushort_t* kv   = (ushort_t*)(ws + 19660800);       // 25,165,824 B
  float*    Sp   = (float*)   (ws + 44826624);       //  6,291,456 B
  ushort_t* S    = (ushort_t*)(ws + 51118080);       //    196,608 B
  ushort_t* Tt   = (ushort_t*)(ws + 51314688);       //  2,359,296 B
  float*    cvec = (float*)   (ws + 53673984);       //      6,144 B

  // 0) all converts fused: x->xb, KV-cols->wqt^T, Wq rows->wqr
  conv_all_k<<<dim3(3648), 256, 0, stream>>>(x, w_qkv, xb, wqt, wqr);
  // 1) kv = x @ w_kv + b_kv -> bf16 [8192][1536]  (32 m x 8 n = 256 blocks)
  g256x192_k<true><<<dim3(256, 1), 512, 0, stream>>>(
      xb, 768, 0LL, wqt + 768 * 768, 768, 0LL, b_qkv + 768, 0LL,
      kv, 1536, 0LL, 768, 8);
  // 2) per-(b,h) partial K^T V over 16 n-chunks
  kv_k<<<dim3(24, 16), 256, 0, stream>>>(kv, Sp);
  // 3) reduce + 1/8
  sred_k<<<dim3(384), 256, 0, stream>>>(Sp, S);
  // 4) Tt[b] = (blockstack_h(S_h @ Wproj_h))^T
  t_gemm_k<<<dim3(12, 24), 256, 0, stream>>>(S, w_proj, Tt);
  // 5) Ut[b] = (Wq @ T[b])^T ; cvec[b] = bq @ T[b] + b_proj  (fused)
  ugcv_k<<<dim3(672), 256, 0, stream>>>(Tt, wqr, b_qkv, b_proj, Ut, cvec);
  // 6) out[b] = x[b] @ U[b] + cvec[b]  (32 m x 4 n per z, z=2 -> 256 blocks)
  g128x192_k<false><<<dim3(128, 2), 512, 0, stream>>>(
      xb, 768, 4096LL * 768, Ut, 768, 768LL * 768, cvec, 768LL,
      out, 768, 4096LL * 768, 768, 4);
}